// Round 3
// baseline (518.931 us; speedup 1.0000x reference)
//
#include <hip/hip_runtime.h>
#include <math.h>

typedef short v8s __attribute__((ext_vector_type(8)));
typedef short v4s __attribute__((ext_vector_type(4)));
typedef float v4f __attribute__((ext_vector_type(4)));

__device__ __forceinline__ float b2f(unsigned short u) {
    return __uint_as_float(((unsigned)u) << 16);
}
__device__ __forceinline__ unsigned short f2b(float f) {
    unsigned u = __float_as_uint(f);
    unsigned r = (u + 0x7FFF + ((u >> 16) & 1)) >> 16;
    return (unsigned short)r;
}

// async global->LDS, 16B per lane; lds dest is wave-uniform base + lane*16
__device__ __forceinline__ void gl_lds16(const unsigned short* g, unsigned short* l) {
    __builtin_amdgcn_global_load_lds(
        (const __attribute__((address_space(1))) void*)g,
        (__attribute__((address_space(3))) void*)l,
        16, 0, 0);
}

// ---------------- zero fill ----------------
__global__ __launch_bounds__(256) void zero_fill(float* __restrict__ p, int n) {
    int i = blockIdx.x * 256 + threadIdx.x;
    if (i < n) p[i] = 0.0f;
}

// ---------------- LN1 fused: fp32 x -> bf16 normed (float2 vectorized) ----------------
__global__ __launch_bounds__(256) void ln_apply(const float* __restrict__ x,
                                                const float* __restrict__ g,
                                                const float* __restrict__ bt,
                                                unsigned short* __restrict__ out) {
    size_t row = blockIdx.x;
    const float2* p = (const float2*)(x + row * 512);
    int t = threadIdx.x;
    float2 v = p[t];
    float s = v.x + v.y, s2 = v.x * v.x + v.y * v.y;
    for (int o = 32; o > 0; o >>= 1) {
        s += __shfl_down(s, o);
        s2 += __shfl_down(s2, o);
    }
    __shared__ float rs[4], rq[4];
    int wave = t >> 6, lane = t & 63;
    if (lane == 0) { rs[wave] = s; rq[wave] = s2; }
    __syncthreads();
    float ts = rs[0] + rs[1] + rs[2] + rs[3];
    float tq = rq[0] + rq[1] + rq[2] + rq[3];
    float mean = ts * (1.0f / 512.0f);
    float var = tq * (1.0f / 512.0f) - mean * mean;
    float inv = rsqrtf(var + 1e-5f);
    float2 gg = ((const float2*)g)[t];
    float2 bb = ((const float2*)bt)[t];
    ushort2 o2;
    o2.x = f2b((v.x - mean) * inv * gg.x + bb.x);
    o2.y = f2b((v.y - mean) * inv * gg.y + bb.y);
    *(ushort2*)&out[row * 512 + 2 * t] = o2;
}

// ---------------- weight transpose + fp32->bf16 ----------------
__global__ __launch_bounds__(256) void transpose_f2b(const float* __restrict__ in,
                                                     unsigned short* __restrict__ out,
                                                     int R, int C) {
    __shared__ unsigned short tile[32][33];
    int c0 = blockIdx.x * 32, r0 = blockIdx.y * 32;
    int tx = threadIdx.x, ty = threadIdx.y;
    for (int j = 0; j < 32; j += 8)
        tile[ty + j][tx] = f2b(in[(size_t)(r0 + ty + j) * C + c0 + tx]);
    __syncthreads();
    for (int j = 0; j < 32; j += 8)
        out[(size_t)(c0 + ty + j) * R + r0 + tx] = tile[tx][ty + j];
}

// ================================================================================
// 256x128-tile GEMM, K=512 (16 K-tiles of BK=32), 8 waves (4Mx2N), 512 threads.
// 3-slot LDS K-tile ring (3 x (16KB A + 8KB B) = 72KB -> 2 blocks/CU) with
// counted vmcnt: each thread issues exactly 3 gl_lds per K-tile (2 A, 1 B);
// loads for tile t+2 issued during t (slot (t+2)%3 last read at t-1, one
// barrier earlier); at tile-t top, vmcnt(3) retires exactly tile t's loads
// (FIFO), keeping t+1's 3 in flight; vmcnt(0) only on the final tile.
// T2 both-sides granule swizzle (c = (g&3) ^ ((row>>1)&3)) on staging source
// and fragment reads -> conflict-free ds_read_b128 (verified 0 in r1/r2).
// T1 bijective XCD swizzle; T5 setprio around the 16-MFMA cluster.
// Epilogue stages the 256x128 bf16 C-tile in the (reused) ring LDS with a
// per-row granule-XOR layout, then streams out coalesced v8s stores.
// ================================================================================
template <int NB, bool QKV>
__global__ __launch_bounds__(512, 4) void gemm256(const unsigned short* __restrict__ A,
                                                  const unsigned short* __restrict__ Bt,
                                                  const float* __restrict__ bias,
                                                  unsigned short* __restrict__ o0,
                                                  unsigned short* __restrict__ o1,
                                                  unsigned short* __restrict__ o2) {
    __shared__ __align__(16) unsigned short LB[3][12288];  // slot: A[0..8191], B[8192..12287]
    int t = threadIdx.x;
    int wave = t >> 6, lane = t & 63;
    int wm = wave >> 1, wn = wave & 1;           // 4 M-quarters x 2 N-halves
    int mrow = lane & 15, kq4 = lane >> 4;
    // XCD-aware bijective chunked swizzle (gridDim.x % 8 == 0)
    int nwg = gridDim.x;
    int cpx = nwg >> 3;
    int bid = blockIdx.x;
    int swz = (bid & 7) * cpx + (bid >> 3);
    int n0 = (swz % NB) * 128;
    int m0 = (swz / NB) * 256;
    const unsigned short* Ab = A + (size_t)m0 * 512;
    const unsigned short* Bb = Bt + (size_t)n0 * 512;
    // staging: A granules g=t and g=t+512 (1024 total, 256 rows x 4),
    //          B granule  g=t (512 total, 128 rows x 4); source col-granule
    //          c = (g&3) ^ ((row>>1)&3); LDS dest linear (wave base + lane*16).
    int rA0 = t >> 2;
    int cA0 = (((t & 3) ^ ((rA0 >> 1) & 3)) * 8);
    int rA1 = 128 + (t >> 2);
    int cA1 = (((t & 3) ^ ((rA1 >> 1) & 3)) * 8);
    size_t srcA0 = (size_t)rA0 * 512 + cA0;
    size_t srcA1 = (size_t)rA1 * 512 + cA1;
    unsigned offA0 = wave * 512;
    unsigned offA1 = 4096 + wave * 512;
    unsigned offB  = 8192 + wave * 512;
    v4f acc[4][4] = {};
    int swr = ((kq4 ^ ((mrow >> 1) & 3)) * 8);

#define STAGE(kt, slot)                                          \
    do {                                                         \
        const unsigned short* aS = Ab + (size_t)(kt) * 32;       \
        const unsigned short* bS = Bb + (size_t)(kt) * 32;       \
        gl_lds16(aS + srcA0, &LB[slot][offA0]);                  \
        gl_lds16(aS + srcA1, &LB[slot][offA1]);                  \
        gl_lds16(bS + srcA0, &LB[slot][offB]);                   \
    } while (0)

    STAGE(0, 0);
    STAGE(1, 1);
    for (int kt = 0; kt < 16; ++kt) {
        if (kt < 15) {
            asm volatile("s_waitcnt vmcnt(3)" ::: "memory");
        } else {
            asm volatile("s_waitcnt vmcnt(0)" ::: "memory");
        }
        __builtin_amdgcn_s_barrier();
        asm volatile("" ::: "memory");
        if (kt + 2 < 16) STAGE(kt + 2, (kt + 2) % 3);
        const unsigned short* as = LB[kt % 3];
        const unsigned short* bs = LB[kt % 3] + 8192;
        v8s af[4], bf[4];
#pragma unroll
        for (int i = 0; i < 4; i++)
            af[i] = *(const v8s*)&as[(wm * 64 + i * 16 + mrow) * 32 + swr];
#pragma unroll
        for (int j = 0; j < 4; j++)
            bf[j] = *(const v8s*)&bs[(wn * 64 + j * 16 + mrow) * 32 + swr];
        __builtin_amdgcn_s_setprio(1);
#pragma unroll
        for (int i = 0; i < 4; i++)
#pragma unroll
            for (int j = 0; j < 4; j++)
                acc[i][j] = __builtin_amdgcn_mfma_f32_16x16x32_bf16(af[i], bf[j], acc[i][j], 0, 0, 0);
        __builtin_amdgcn_s_setprio(0);
    }
#undef STAGE
    // ---------------- epilogue: stage C tile in LDS, stream out coalesced ----------
    __syncthreads();
    unsigned short* CT = &LB[0][0];  // 256 rows x 128 cols bf16 = 64KB (fits 72KB ring)
    bool doRelu = QKV && (n0 < 1024);
#pragma unroll
    for (int j = 0; j < 4; j++) {
        int col = wn * 64 + j * 16 + mrow;          // tile-local col 0..127
        float bv = bias[n0 + col];
        int gr = col >> 3;                           // granule 0..15
        int gb = col & 7;
#pragma unroll
        for (int i = 0; i < 4; i++) {
            int rowb = wm * 64 + i * 16 + kq4 * 4;
#pragma unroll
            for (int r = 0; r < 4; r++) {
                int row = rowb + r;
                float v = acc[i][j][r] + bv;
                if (doRelu) v = fmaxf(v, 0.0f);
                CT[row * 128 + ((gr ^ (row & 7)) << 3) + gb] = f2b(v);
            }
        }
    }
    __syncthreads();
    unsigned short* base;
    int cb;
    if (QKV) {
        int seg = n0 >> 9;
        base = (seg == 0) ? o0 : ((seg == 1) ? o1 : o2);
        cb = n0 & 511;
    } else {
        base = o0;
        cb = n0;
    }
#pragma unroll
    for (int p = 0; p < 8; p++) {
        int g = p * 512 + t;
        int row = g >> 4, gl = g & 15;
        int phys = gl ^ (row & 7);
        v8s v = *(const v8s*)&CT[row * 128 + (phys << 3)];
        *(v8s*)&base[(size_t)(m0 + row) * 512 + cb + gl * 8] = v;
    }
}

// ---------------- kv partials: per (bh, chunk of 128 rows), no atomics ----------------
__global__ __launch_bounds__(256) void kv_part(const unsigned short* __restrict__ kbuf,
                                               const unsigned short* __restrict__ vbuf,
                                               float* __restrict__ kvp,
                                               float* __restrict__ ksp) {
    int bh = blockIdx.x;   // 0..63
    int b = bh >> 3, h = bh & 7;
    int nc = blockIdx.y;   // 0..31
    __shared__ __align__(16) unsigned short kb[64 * 64];
    __shared__ __align__(16) unsigned short vb[64 * 64];
    int t = threadIdx.x;
    int dk0 = (t >> 4) * 4;
    int dv0 = (t & 15) * 4;
    float acc[4][4] = {};
    float ks[4] = {};
    int lr = t >> 2, lc = (t & 3) * 16;
    for (int n0 = nc * 128; n0 < nc * 128 + 128; n0 += 64) {
        __syncthreads();
        size_t base = ((size_t)(b * 4096 + n0 + lr)) * 512 + h * 64;
        *(v8s*)&kb[lr * 64 + lc]     = *(const v8s*)&kbuf[base + lc];
        *(v8s*)&kb[lr * 64 + lc + 8] = *(const v8s*)&kbuf[base + lc + 8];
        *(v8s*)&vb[lr * 64 + lc]     = *(const v8s*)&vbuf[base + lc];
        *(v8s*)&vb[lr * 64 + lc + 8] = *(const v8s*)&vbuf[base + lc + 8];
        __syncthreads();
#pragma unroll 4
        for (int nn = 0; nn < 64; nn++) {
            v4s kr = *(const v4s*)&kb[nn * 64 + dk0];
            v4s vr = *(const v4s*)&vb[nn * 64 + dv0];
            float kf[4], vf[4];
#pragma unroll
            for (int i = 0; i < 4; i++) { kf[i] = b2f((unsigned short)kr[i]); vf[i] = b2f((unsigned short)vr[i]); }
#pragma unroll
            for (int i = 0; i < 4; i++) {
#pragma unroll
                for (int j = 0; j < 4; j++) acc[i][j] += kf[i] * vf[j];
            }
            if ((t & 15) == 0) {
#pragma unroll
                for (int i = 0; i < 4; i++) ks[i] += kf[i];
            }
        }
    }
    float* dst = kvp + ((size_t)(bh * 32 + nc)) * 4096;
#pragma unroll
    for (int i = 0; i < 4; i++)
        *(float4*)&dst[(dk0 + i) * 64 + dv0] = make_float4(acc[i][0], acc[i][1], acc[i][2], acc[i][3]);
    if ((t & 15) == 0) {
        float* kd = ksp + ((size_t)(bh * 32 + nc)) * 64;
#pragma unroll
        for (int i = 0; i < 4; i++) kd[dk0 + i] = ks[i];
    }
}

// ---------------- kv reduce: sum 32 partials -> kvb, ksum ----------------
__global__ __launch_bounds__(256) void kv_reduce(const float* __restrict__ kvp,
                                                 const float* __restrict__ ksp,
                                                 float* __restrict__ kvb,
                                                 float* __restrict__ ksum) {
    int tid = blockIdx.x * 256 + threadIdx.x;
    int bh = tid >> 12, e = tid & 4095;
    float s = 0.0f;
#pragma unroll 8
    for (int c = 0; c < 32; c++) s += kvp[((size_t)(bh * 32 + c)) * 4096 + e];
    kvb[(size_t)bh * 4096 + e] = s;
    if (tid < 4096) {
        int bh2 = tid >> 6, dk = tid & 63;
        float t = 0.0f;
#pragma unroll 8
        for (int c = 0; c < 32; c++) t += ksp[((size_t)(bh2 * 32 + c)) * 64 + dk];
        ksum[tid] = t;
    }
}

// ---------------- attn; IN-PLACE over q ----------------
__global__ __launch_bounds__(256) void attn_kernel(unsigned short* qa,
                                                   const float* __restrict__ kv,
                                                   const float* __restrict__ ksum) {
    int bh = blockIdx.y;
    int b = bh >> 3, h = bh & 7;
    int nt = blockIdx.x;
    __shared__ float kvs[64 * 64];
    __shared__ float nrm[64];
    int t = threadIdx.x;
    for (int i = t; i < 4096; i += 256) kvs[i] = kv[(size_t)bh * 4096 + i];
    if (t < 64) nrm[t] = fmaxf(ksum[bh * 64 + t], 100.0f);
    __syncthreads();
    int n = nt * 256 + t;
    unsigned short* qp = qa + ((size_t)(b * 4096 + n)) * 512 + h * 64;
    float qf[64];
#pragma unroll
    for (int i = 0; i < 64; i += 8) {
        v8s v = *(const v8s*)&qp[i];
#pragma unroll
        for (int j = 0; j < 8; j++) qf[i + j] = b2f((unsigned short)v[j]);
    }
    float denom = 0.0f;
#pragma unroll
    for (int d = 0; d < 64; d++) denom += qf[d] * nrm[d];
    denom = fmaxf(denom, 100.0f);
    float inv = 1.0f / denom;
#pragma unroll
    for (int dv = 0; dv < 64; dv += 16) {
        float o[16] = {};
        for (int dk = 0; dk < 64; dk++) {
            float q = qf[dk];
#pragma unroll
            for (int i = 0; i < 16; i++) o[i] += q * kvs[dk * 64 + dv + i];
        }
        v8s ov0, ov1;
#pragma unroll
        for (int i = 0; i < 8; i++) {
            ov0[i] = (short)f2b(o[i] * inv);
            ov1[i] = (short)f2b(o[i + 8] * inv);
        }
        *(v8s*)&qp[dv] = ov0;
        *(v8s*)&qp[dv + 8] = ov1;
    }
}

// ---------------- fused LN2 + transpose: [B,N,C] bf16 -> LN -> [B,C,N] bf16 ----------
__global__ __launch_bounds__(256) void ln2_transpose(const unsigned short* __restrict__ in,
                                                     const float* __restrict__ g,
                                                     const float* __restrict__ bt,
                                                     unsigned short* __restrict__ out) {
    int bid = blockIdx.x;
    int b = bid >> 6;
    int n0 = (bid & 63) * 64;
    __shared__ float gs[512], bs[512];
    __shared__ __align__(16) unsigned short tile[512 * 64];  // [c][n-local], XOR-swizzled
    int t = threadIdx.x;
    for (int i = t; i < 512; i += 256) { gs[i] = g[i]; bs[i] = bt[i]; }
    int nl = t >> 2, sub = t & 3;
    const unsigned short* src = in + ((size_t)(b * 4096 + n0 + nl)) * 512 + sub * 8;
    v8s vv[16];
#pragma unroll
    for (int c16 = 0; c16 < 16; c16++)
        vv[c16] = *(const v8s*)&src[c16 * 32];
    float s = 0.f, s2 = 0.f;
#pragma unroll
    for (int c16 = 0; c16 < 16; c16++)
#pragma unroll
        for (int j = 0; j < 8; j++) {
            float f = b2f((unsigned short)vv[c16][j]);
            s += f; s2 += f * f;
        }
    s += __shfl_xor(s, 1); s2 += __shfl_xor(s2, 1);
    s += __shfl_xor(s, 2); s2 += __shfl_xor(s2, 2);
    float mean = s * (1.f / 512.f);
    float var = s2 * (1.f / 512.f) - mean * mean;
    float inv = rsqrtf(var + 1e-5f);
    __syncthreads();   // gs/bs ready
#pragma unroll
    for (int c16 = 0; c16 < 16; c16++) {
        int cb_ = sub * 8 + c16 * 32;
#pragma unroll
        for (int j = 0; j < 8; j++) {
            int c = cb_ + j;
            float f = b2f((unsigned short)vv[c16][j]);
            float y = (f - mean) * inv * gs[c] + bs[c];
            tile[c * 64 + ((((nl >> 3) ^ (c & 7)) << 3) | (nl & 7))] = f2b(y);
        }
    }
    __syncthreads();
    unsigned short* dst = out + ((size_t)b * 512) * 4096 + n0;
#pragma unroll
    for (int p = 0; p < 16; p++) {
        int chunk = p * 256 + t;
        int c = chunk >> 3, gseg = chunk & 7;
        int phys = gseg ^ (c & 7);
        v8s v = *(const v8s*)&tile[c * 64 + phys * 8];
        *(v8s*)&dst[(size_t)c * 4096 + gseg * 8] = v;
    }
}

// ---------------- depthwise conv 7x7 + GELU + BN stats; column-sliding ----------
__global__ __launch_bounds__(256) void dwconv7_gelu(const unsigned short* __restrict__ in,
                                                    const float* __restrict__ w,
                                                    const float* __restrict__ bias,
                                                    unsigned short* __restrict__ out,
                                                    float* __restrict__ bn_sum,
                                                    float* __restrict__ bn_sumsq) {
    int bc = blockIdx.x;
    int c = bc & 511;
    __shared__ float img[70 * 72];
    __shared__ float wsm[49];
    __shared__ float r1[4], r2[4];
    int t = threadIdx.x;
    int tx = t & 63, ty = t >> 6;
    for (int i = t; i < 70 * 72; i += 256) img[i] = 0.0f;
    if (t < 49) wsm[t] = w[c * 49 + t];
    __syncthreads();
    const unsigned short* src = in + (size_t)bc * 4096;
#pragma unroll
    for (int q = t; q < 512; q += 256) {
        v8s v = *(const v8s*)&src[q * 8];
        float* ip = &img[((q >> 3) + 3) * 72 + (q & 7) * 8 + 3];
#pragma unroll
        for (int j = 0; j < 8; j++) ip[j] = b2f((unsigned short)v[j]);
    }
    __syncthreads();
    float wt[49];
#pragma unroll
    for (int i = 0; i < 49; i++) wt[i] = wsm[i];
    float bv = bias[c];
    float acc[16];
#pragma unroll
    for (int i = 0; i < 16; i++) acc[i] = bv;
    int h0 = ty * 16;
#pragma unroll
    for (int rr = 0; rr < 22; rr++) {
        float v[7];
#pragma unroll
        for (int kw = 0; kw < 7; kw++) v[kw] = img[(h0 + rr) * 72 + tx + kw];
#pragma unroll
        for (int kh = 0; kh < 7; kh++) {
            int o = rr - kh;
            if (o >= 0 && o <= 15) {
                float dot = v[0] * wt[kh * 7];
#pragma unroll
                for (int kw = 1; kw < 7; kw++) dot += v[kw] * wt[kh * 7 + kw];
                acc[o] += dot;
            }
        }
    }
    float s = 0.0f, s2 = 0.0f;
    unsigned short* dst = out + (size_t)bc * 4096;
#pragma unroll
    for (int i = 0; i < 16; i++) {
        float a = acc[i];
        float ge = 0.5f * a * (1.0f + erff(a * 0.70710678118f));
        dst[(h0 + i) * 64 + tx] = f2b(ge);
        s += ge;
        s2 += ge * ge;
    }
    for (int o = 32; o > 0; o >>= 1) {
        s += __shfl_down(s, o);
        s2 += __shfl_down(s2, o);
    }
    int lane = t & 63;
    if (lane == 0) { r1[ty] = s; r2[ty] = s2; }
    __syncthreads();
    if (t == 0) {
        atomicAdd(&bn_sum[c], r1[0] + r1[1] + r1[2] + r1[3]);
        atomicAdd(&bn_sumsq[c], r2[0] + r2[1] + r2[2] + r2[3]);
    }
}

__global__ void bn_finalize(const float* __restrict__ s, const float* __restrict__ s2,
                            const float* __restrict__ g, const float* __restrict__ b,
                            float2* __restrict__ ab) {
    int c = blockIdx.x * blockDim.x + threadIdx.x;
    if (c >= 512) return;
    float m = s[c] * (1.0f / 32768.0f);
    float var = s2[c] * (1.0f / 32768.0f) - m * m;
    float inv = rsqrtf(var + 1e-5f);
    float sc = g[c] * inv;
    ab[c] = make_float2(sc, b[c] - m * sc);
}

// ---------------- depthwise conv 7x7 with BN affine on load; column-sliding -------------------
__global__ __launch_bounds__(256) void dwconv7_bn(const unsigned short* __restrict__ in,
                                                  const float2* __restrict__ bnab,
                                                  const float* __restrict__ w,
                                                  const float* __restrict__ bias,
                                                  unsigned short* __restrict__ out) {
    int bc = blockIdx.x;
    int c = bc & 511;
    __shared__ float img[70 * 72];
    __shared__ float wsm[49];
    int t = threadIdx.x;
    int tx = t & 63, ty = t >> 6;
    for (int i = t; i < 70 * 72; i += 256) img[i] = 0.0f;
    if (t < 49) wsm[t] = w[c * 49 + t];
    __syncthreads();
    float2 ab = bnab[c];
    const unsigned short* src = in + (size_t)bc * 4096;
#pragma unroll
    for (int q = t; q < 512; q += 256) {
        v8s v = *(const v8s*)&src[q * 8];
        float* ip = &img[((q >> 3) + 3) * 72 + (q & 7) * 8 + 3];
#pragma unroll
        for (int j = 0; j < 8; j++) ip[j] = b2f((unsigned short)v[j]) * ab.x + ab.y;
    }
    __syncthreads();
    float wt[49];
#pragma unroll
    for (int i = 0; i < 49; i++) wt[i] = wsm[i];
    float bv = bias[c];
    float acc[16];
#pragma unroll
    for (int i = 0; i < 16; i++) acc[i] = bv;
    int h0 = ty * 16;
#pragma unroll
    for (int rr = 0; rr < 22; rr++) {
        float v[7];
#pragma unroll
        for (int kw = 0; kw < 7; kw++) v[kw] = img[(h0 + rr) * 72 + tx + kw];
#pragma unroll
        for (int kh = 0; kh < 7; kh++) {
            int o = rr - kh;
            if (o >= 0 && o <= 15) {
                float dot = v[0] * wt[kh * 7];
#pragma unroll
                for (int kw = 1; kw < 7; kw++) dot += v[kw] * wt[kh * 7 + kw];
                acc[o] += dot;
            }
        }
    }
    unsigned short* dst = out + (size_t)bc * 4096;
#pragma unroll
    for (int i = 0; i < 16; i++)
        dst[(h0 + i) * 64 + tx] = f2b(acc[i]);
}

// ---------------- final: out = x(f32) + attn(bf16) + y2^T(bf16) -> f32 (vectorized) -----------
__global__ __launch_bounds__(256) void final_add(const float* __restrict__ x,
                                                 const unsigned short* __restrict__ attn,
                                                 const unsigned short* __restrict__ y2,
                                                 float* __restrict__ out) {
    __shared__ unsigned short tile[32][36];
    int b = blockIdx.z;
    int c0 = blockIdx.x * 32, n0 = blockIdx.y * 32;
    int t = threadIdx.x;
    {
        int c = t >> 3, n4 = (t & 7) * 4;
        ushort4 v = *(const ushort4*)&y2[((size_t)(b * 512 + c0 + c)) * 4096 + n0 + n4];
        tile[c][n4] = v.x; tile[c][n4 + 1] = v.y; tile[c][n4 + 2] = v.z; tile[c][n4 + 3] = v.w;
    }
    __syncthreads();
    int nl = t >> 3, cl = (t & 7) * 4;
    size_t idx = ((size_t)(b * 4096 + n0 + nl)) * 512 + c0 + cl;
    float4 xv = *(const float4*)&x[idx];
    ushort4 av = *(const ushort4*)&attn[idx];
    float4 o;
    o.x = xv.x + b2f(av.x) + b2f(tile[cl][nl]);
    o.y = xv.y + b2f(av.y) + b2f(tile[cl + 1][nl]);
    o.z = xv.z + b2f(av.z) + b2f(tile[cl + 2][nl]);
    o.w = xv.w + b2f(av.w) + b2f(tile[cl + 3][nl]);
    *(float4*)&out[idx] = o;
}

// ------------------------------------------------------------------------------------------------
extern "C" void kernel_launch(void* const* d_in, const int* in_sizes, int n_in,
                              void* d_out, int out_size, void* d_ws, size_t ws_size,
                              hipStream_t stream) {
    const float* x     = (const float*)d_in[0];
    const float* qkv_w = (const float*)d_in[1];
    const float* qkv_b = (const float*)d_in[2];
    const float* out_w = (const float*)d_in[3];
    const float* out_b = (const float*)d_in[4];
    const float* pre_g = (const float*)d_in[5];
    const float* pre_b = (const float*)d_in[6];
    const float* lcm_g = (const float*)d_in[7];
    const float* lcm_b = (const float*)d_in[8];
    const float* ci_w  = (const float*)d_in[9];
    const float* ci_b  = (const float*)d_in[10];
    const float* bn_g  = (const float*)d_in[11];
    const float* bn_b  = (const float*)d_in[12];
    const float* co_w  = (const float*)d_in[13];
    const float* co_b  = (const float*)d_in[14];

    char* ws = (char*)d_ws;
    const size_t SLOT = 33554432;  // 32768*512*2 bytes (bf16)
    unsigned short* S0 = (unsigned short*)(ws);               // q -> attn -> xi -> y2
    unsigned short* S1 = (unsigned short*)(ws + SLOT);        // k -> attn_out(bf16)
    unsigned short* S2 = (unsigned short*)(ws + 2 * SLOT);    // v -> y
    const size_t MISC = 3 * SLOT;                             // 96MB
    unsigned short* wT1 = (unsigned short*)(ws + MISC);                 // 1.5MB bf16
    unsigned short* wT2 = (unsigned short*)(ws + MISC + 1572864);       // 0.5MB bf16
    float* kvb          = (float*)(ws + MISC + 2097152);                // 1MB
    float* ksum         = (float*)(ws + MISC + 2097152 + 1048576);      // 16KB
    float* bn_sum       = (float*)(ws + MISC + 2097152 + 1048576 + 16384);        // 2KB
    float* bn_sumsq     = (float*)(ws + MISC + 2097152 + 1048576 + 16384 + 2048); // 2KB
    float2* bnab        = (float2*)(ws + MISC + 3166208);               // 4KB
    float* ksp          = (float*)(ws + MISC + 3170304);                // 512KB
    float* outp         = (float*)d_out;

    // d_out doubles as scratch before final_add fully overwrites it:
    unsigned short* normed = (unsigned short*)d_out;                    // 32MB bf16
    float* kvp             = (float*)((char*)d_out + SLOT);             // 32MB fp32 partials

    dim3 tb(32, 8);
    transpose_f2b<<<dim3(48, 16), tb, 0, stream>>>(qkv_w, wT1, 512, 1536);
    transpose_f2b<<<dim3(16, 16), tb, 0, stream>>>(out_w, wT2, 512, 512);
    zero_fill<<<4, 256, 0, stream>>>(bn_sum, 1024);  // bn_sum + bn_sumsq
    ln_apply<<<32768, 256, 0, stream>>>(x, pre_g, pre_b, normed);
    // M=32768/256=128, N=1536/128=12 -> 1536 blocks (%8==0)
    gemm256<12, true><<<1536, 512, 0, stream>>>(normed, wT1, qkv_b, S0, S1, S2);
    kv_part<<<dim3(64, 32), 256, 0, stream>>>(S1, S2, kvp, ksp);
    kv_reduce<<<1024, 256, 0, stream>>>(kvp, ksp, kvb, ksum);
    attn_kernel<<<dim3(16, 64), 256, 0, stream>>>(S0, kvb, ksum);
    // M=128, N=512/128=4 -> 512 blocks (%8==0)
    gemm256<4, false><<<512, 512, 0, stream>>>(S0, wT2, out_b, S1, S1, S1);
    // fused LN2 + transpose: S1 [B,N,C] -> S0 [B,C,N]
    ln2_transpose<<<512, 256, 0, stream>>>(S1, lcm_g, lcm_b, S0);
    dwconv7_gelu<<<4096, 256, 0, stream>>>(S0, ci_w, ci_b, S2, bn_sum, bn_sumsq);
    bn_finalize<<<2, 256, 0, stream>>>(bn_sum, bn_sumsq, bn_g, bn_b, bnab);
    dwconv7_bn<<<4096, 256, 0, stream>>>(S2, bnab, co_w, co_b, S0);
    final_add<<<dim3(16, 128, 8), tb.x * tb.y, 0, stream>>>(x, S1, S0, outp);
}

// Round 4
// 436.485 us; speedup vs baseline: 1.1889x; 1.1889x over previous
//
#include <hip/hip_runtime.h>
#include <math.h>

typedef short v8s __attribute__((ext_vector_type(8)));
typedef short v4s __attribute__((ext_vector_type(4)));
typedef float v4f __attribute__((ext_vector_type(4)));

__device__ __forceinline__ float b2f(unsigned short u) {
    return __uint_as_float(((unsigned)u) << 16);
}
__device__ __forceinline__ unsigned short f2b(float f) {
    unsigned u = __float_as_uint(f);
    unsigned r = (u + 0x7FFF + ((u >> 16) & 1)) >> 16;
    return (unsigned short)r;
}
__device__ __forceinline__ int swz8(int row) { return (row & 7) ^ ((row >> 3) & 7); }

// async global->LDS, 16B per lane; lds dest is wave-uniform base + lane*16
__device__ __forceinline__ void gl_lds16(const unsigned short* g, unsigned short* l) {
    __builtin_amdgcn_global_load_lds(
        (const __attribute__((address_space(1))) void*)g,
        (__attribute__((address_space(3))) void*)l,
        16, 0, 0);
}

// ---------------- zero fill ----------------
__global__ __launch_bounds__(256) void zero_fill(float* __restrict__ p, int n) {
    int i = blockIdx.x * 256 + threadIdx.x;
    if (i < n) p[i] = 0.0f;
}

// ---------------- LN1 fused: fp32 x -> bf16 normed (float2 vectorized) ----------------
__global__ __launch_bounds__(256) void ln_apply(const float* __restrict__ x,
                                                const float* __restrict__ g,
                                                const float* __restrict__ bt,
                                                unsigned short* __restrict__ out) {
    size_t row = blockIdx.x;
    const float2* p = (const float2*)(x + row * 512);
    int t = threadIdx.x;
    float2 v = p[t];
    float s = v.x + v.y, s2 = v.x * v.x + v.y * v.y;
    for (int o = 32; o > 0; o >>= 1) {
        s += __shfl_down(s, o);
        s2 += __shfl_down(s2, o);
    }
    __shared__ float rs[4], rq[4];
    int wave = t >> 6, lane = t & 63;
    if (lane == 0) { rs[wave] = s; rq[wave] = s2; }
    __syncthreads();
    float ts = rs[0] + rs[1] + rs[2] + rs[3];
    float tq = rq[0] + rq[1] + rq[2] + rq[3];
    float mean = ts * (1.0f / 512.0f);
    float var = tq * (1.0f / 512.0f) - mean * mean;
    float inv = rsqrtf(var + 1e-5f);
    float2 gg = ((const float2*)g)[t];
    float2 bb = ((const float2*)bt)[t];
    ushort2 o2;
    o2.x = f2b((v.x - mean) * inv * gg.x + bb.x);
    o2.y = f2b((v.y - mean) * inv * gg.y + bb.y);
    *(ushort2*)&out[row * 512 + 2 * t] = o2;
}

// ---------------- weight transpose + fp32->bf16 ----------------
__global__ __launch_bounds__(256) void transpose_f2b(const float* __restrict__ in,
                                                     unsigned short* __restrict__ out,
                                                     int R, int C) {
    __shared__ unsigned short tile[32][33];
    int c0 = blockIdx.x * 32, r0 = blockIdx.y * 32;
    int tx = threadIdx.x, ty = threadIdx.y;
    for (int j = 0; j < 32; j += 8)
        tile[ty + j][tx] = f2b(in[(size_t)(r0 + ty + j) * C + c0 + tx]);
    __syncthreads();
    for (int j = 0; j < 32; j += 8)
        out[(size_t)(c0 + ty + j) * R + r0 + tx] = tile[tx][ty + j];
}

// ================================================================================
// 256x128-tile GEMM, K=512 (16 K-tiles of BK=32), 8 waves (4Mx2N), 512 threads.
// 3-slot LDS K-tile ring, counted vmcnt(3), T1/T2/T5 as in r3.
// Epilogue: C tile staged in LDS (stride 136, granule swizzle gr ^ swz8(row)).
// q / gemm2 outputs: coalesced row-major v8s stores.
// k,v outputs (QKV, n0>=512): written TRANSPOSED as kT/vT [bh][d][n] so the
// downstream KV GEMM and attention consume them with MFMA directly.
// ================================================================================
template <int NB, bool QKV>
__global__ __launch_bounds__(512, 4) void gemm256(const unsigned short* __restrict__ A,
                                                  const unsigned short* __restrict__ Bt,
                                                  const float* __restrict__ bias,
                                                  unsigned short* __restrict__ o0,
                                                  unsigned short* __restrict__ o1,
                                                  unsigned short* __restrict__ o2) {
    __shared__ __align__(16) unsigned short LB[3][12288];  // slot: A[0..8191], B[8192..12287]
    int t = threadIdx.x;
    int wave = t >> 6, lane = t & 63;
    int wm = wave >> 1, wn = wave & 1;           // 4 M-quarters x 2 N-halves
    int mrow = lane & 15, kq4 = lane >> 4;
    int nwg = gridDim.x;
    int cpx = nwg >> 3;
    int bid = blockIdx.x;
    int swz = (bid & 7) * cpx + (bid >> 3);
    int n0 = (swz % NB) * 128;
    int m0 = (swz / NB) * 256;
    const unsigned short* Ab = A + (size_t)m0 * 512;
    const unsigned short* Bb = Bt + (size_t)n0 * 512;
    int rA0 = t >> 2;
    int cA0 = (((t & 3) ^ ((rA0 >> 1) & 3)) * 8);
    int rA1 = 128 + (t >> 2);
    int cA1 = (((t & 3) ^ ((rA1 >> 1) & 3)) * 8);
    size_t srcA0 = (size_t)rA0 * 512 + cA0;
    size_t srcA1 = (size_t)rA1 * 512 + cA1;
    unsigned offA0 = wave * 512;
    unsigned offA1 = 4096 + wave * 512;
    unsigned offB  = 8192 + wave * 512;
    v4f acc[4][4] = {};
    int swr = ((kq4 ^ ((mrow >> 1) & 3)) * 8);

#define STAGE(kt, slot)                                          \
    do {                                                         \
        const unsigned short* aS = Ab + (size_t)(kt) * 32;       \
        const unsigned short* bS = Bb + (size_t)(kt) * 32;       \
        gl_lds16(aS + srcA0, &LB[slot][offA0]);                  \
        gl_lds16(aS + srcA1, &LB[slot][offA1]);                  \
        gl_lds16(bS + srcA0, &LB[slot][offB]);                   \
    } while (0)

    STAGE(0, 0);
    STAGE(1, 1);
    for (int kt = 0; kt < 16; ++kt) {
        if (kt < 15) {
            asm volatile("s_waitcnt vmcnt(3)" ::: "memory");
        } else {
            asm volatile("s_waitcnt vmcnt(0)" ::: "memory");
        }
        __builtin_amdgcn_s_barrier();
        asm volatile("" ::: "memory");
        if (kt + 2 < 16) STAGE(kt + 2, (kt + 2) % 3);
        const unsigned short* as = LB[kt % 3];
        const unsigned short* bs = LB[kt % 3] + 8192;
        v8s af[4], bf[4];
#pragma unroll
        for (int i = 0; i < 4; i++)
            af[i] = *(const v8s*)&as[(wm * 64 + i * 16 + mrow) * 32 + swr];
#pragma unroll
        for (int j = 0; j < 4; j++)
            bf[j] = *(const v8s*)&bs[(wn * 64 + j * 16 + mrow) * 32 + swr];
        __builtin_amdgcn_s_setprio(1);
#pragma unroll
        for (int i = 0; i < 4; i++)
#pragma unroll
            for (int j = 0; j < 4; j++)
                acc[i][j] = __builtin_amdgcn_mfma_f32_16x16x32_bf16(af[i], bf[j], acc[i][j], 0, 0, 0);
        __builtin_amdgcn_s_setprio(0);
    }
#undef STAGE
    // ---------------- epilogue: stage C tile in LDS (stride 136, swizzled) ----------
    __syncthreads();
    unsigned short* CT = &LB[0][0];  // 256 rows x 128 cols, stride 136 shorts
    bool doRelu = QKV && (n0 < 1024);
#pragma unroll
    for (int j = 0; j < 4; j++) {
        int col = wn * 64 + j * 16 + mrow;          // tile-local col 0..127
        float bv = bias[n0 + col];
        int gr = col >> 3, gb = col & 7;
#pragma unroll
        for (int i = 0; i < 4; i++) {
            int rowb = wm * 64 + i * 16 + kq4 * 4;
#pragma unroll
            for (int r = 0; r < 4; r++) {
                int row = rowb + r;
                float v = acc[i][j][r] + bv;
                if (doRelu) v = fmaxf(v, 0.0f);
                CT[row * 136 + ((gr ^ swz8(row)) << 3) + gb] = f2b(v);
            }
        }
    }
    __syncthreads();
    if (!QKV || n0 < 512) {
        // coalesced row-major write (q / gemm2 out)
#pragma unroll
        for (int p = 0; p < 8; p++) {
            int g = p * 512 + t;
            int row = g >> 4, gl = g & 15;
            v8s v = *(const v8s*)&CT[row * 136 + ((gl ^ swz8(row)) << 3)];
            *(v8s*)&o0[(size_t)(m0 + row) * 512 + n0 + gl * 8] = v;
        }
    } else {
        // transposed write: kT (512<=col<1024) or vT (>=1024), layout [bh][d][n]
        unsigned short* Tb = (n0 < 1024) ? o1 : o2;
        int col = t >> 2, sub = t & 3;
        int cglob = n0 + col;
        int hl = (cglob & 511) >> 6, d = cglob & 63;
        int bb = m0 >> 12, gc = m0 & 4095;
        unsigned short* dst = Tb + ((size_t)((bb * 8 + hl) * 64 + d)) * 4096 + gc;
        int cg = col >> 3, cb7 = col & 7;
#pragma unroll
        for (int g = 0; g < 8; g++) {
            v8s v;
#pragma unroll
            for (int e = 0; e < 8; e++) {
                int rr = g * 32 + sub * 8 + e;
                v[e] = (short)CT[rr * 136 + ((cg ^ swz8(rr)) << 3) + cb7];
            }
            *(v8s*)&dst[g * 32 + sub * 8] = v;
        }
    }
}

// ---------------- kv partials via MFMA: KV[dk][dv] = sum_n kT[dk][n]*vT[dv][n] --------
// grid (bh=64, nc=8 chunks of 512 n); 4 waves = 2x2 of 32x32 output.
__global__ __launch_bounds__(256) void kv_part(const unsigned short* __restrict__ kT,
                                               const unsigned short* __restrict__ vT,
                                               float* __restrict__ kvp,
                                               float* __restrict__ ksp) {
    __shared__ __align__(16) unsigned short LB[3][4096];  // slot: K 2048 + V 2048 shorts
    int bh = blockIdx.x, nc = blockIdx.y;
    int t = threadIdx.x;
    int w = t >> 6, lane = t & 63;
    int wdk = w >> 1, wdv = w & 1;
    int mrow = lane & 15, kq4 = lane >> 4;
    const unsigned short* Kb = kT + (size_t)bh * 262144 + nc * 512;
    const unsigned short* Vb = vT + (size_t)bh * 262144 + nc * 512;
    // staging: 64 rows x 4 granules each for K and V; both-sides swizzle
    int rA = t >> 2;
    int lcA = (t & 3) ^ (rA & 3);
    size_t srcoff = (size_t)rA * 4096 + lcA * 8;
    unsigned dstK = w * 512;          // shorts (wave-uniform base)
    unsigned dstV = 2048 + w * 512;
    v4f acc[2][2] = {};
    v4f accs[2] = {};
    v8s ones;
#pragma unroll
    for (int jj = 0; jj < 8; jj++) ones[jj] = (short)0x3F80;

#define KSTAGE(ks, slot)                                         \
    do {                                                         \
        gl_lds16(Kb + (size_t)(ks) * 32 + srcoff, &LB[slot][dstK]); \
        gl_lds16(Vb + (size_t)(ks) * 32 + srcoff, &LB[slot][dstV]); \
    } while (0)

    KSTAGE(0, 0);
    KSTAGE(1, 1);
    for (int ks = 0; ks < 16; ++ks) {
        if (ks < 15) {
            asm volatile("s_waitcnt vmcnt(2)" ::: "memory");
        } else {
            asm volatile("s_waitcnt vmcnt(0)" ::: "memory");
        }
        __builtin_amdgcn_s_barrier();
        asm volatile("" ::: "memory");
        if (ks + 2 < 16) KSTAGE(ks + 2, (ks + 2) % 3);
        const unsigned short* as = LB[ks % 3];
        v8s af[2], bf[2];
#pragma unroll
        for (int i = 0; i < 2; i++) {
            int row = wdk * 32 + i * 16 + mrow;
            af[i] = *(const v8s*)&as[row * 32 + ((kq4 ^ (row & 3)) << 3)];
        }
#pragma unroll
        for (int j = 0; j < 2; j++) {
            int row = wdv * 32 + j * 16 + mrow;
            bf[j] = *(const v8s*)&as[2048 + row * 32 + ((kq4 ^ (row & 3)) << 3)];
        }
#pragma unroll
        for (int i = 0; i < 2; i++)
#pragma unroll
            for (int j = 0; j < 2; j++)
                acc[i][j] = __builtin_amdgcn_mfma_f32_16x16x32_bf16(af[i], bf[j], acc[i][j], 0, 0, 0);
        if (wdv == 0) {
#pragma unroll
            for (int i = 0; i < 2; i++)
                accs[i] = __builtin_amdgcn_mfma_f32_16x16x32_bf16(af[i], ones, accs[i], 0, 0, 0);
        }
    }
#undef KSTAGE
    float* dst = kvp + ((size_t)(bh * 8 + nc)) * 4096;
#pragma unroll
    for (int i = 0; i < 2; i++)
#pragma unroll
        for (int j = 0; j < 2; j++)
#pragma unroll
            for (int r = 0; r < 4; r++) {
                int row = wdk * 32 + i * 16 + kq4 * 4 + r;
                int col = wdv * 32 + j * 16 + mrow;
                dst[row * 64 + col] = acc[i][j][r];
            }
    if (wdv == 0 && mrow == 0) {
        float* kd = ksp + ((size_t)(bh * 8 + nc)) * 64 + wdk * 32;
#pragma unroll
        for (int i = 0; i < 2; i++)
#pragma unroll
            for (int r = 0; r < 4; r++)
                kd[i * 16 + kq4 * 4 + r] = accs[i][r];
    }
}

// ---------------- kv reduce: sum 8 partials -> kvb, ksum ----------------
__global__ __launch_bounds__(256) void kv_reduce(const float* __restrict__ kvp,
                                                 const float* __restrict__ ksp,
                                                 float* __restrict__ kvb,
                                                 float* __restrict__ ksum) {
    int tid = blockIdx.x * 256 + threadIdx.x;
    int bh = tid >> 12, e = tid & 4095;
    float s = 0.0f;
#pragma unroll
    for (int c = 0; c < 8; c++) s += kvp[((size_t)(bh * 8 + c)) * 4096 + e];
    kvb[(size_t)bh * 4096 + e] = s;
    if (tid < 4096) {
        int bh2 = tid >> 6, dk = tid & 63;
        float x = 0.0f;
#pragma unroll
        for (int c = 0; c < 8; c++) x += ksp[(bh2 * 8 + c) * 64 + dk];
        ksum[tid] = x;
    }
}

// ---------------- attn via MFMA; IN-PLACE over q; kv/nrm split hi+lo bf16 -------------
__global__ __launch_bounds__(256) void attn_mfma(unsigned short* __restrict__ qa,
                                                 const float* __restrict__ kv,
                                                 const float* __restrict__ ksum) {
    __shared__ __align__(16) unsigned short olds[4][4096];
    int bh = blockIdx.y;
    int b = bh >> 3, h = bh & 7;
    int t = threadIdx.x;
    int w = t >> 6, lane = t & 63;
    int mrow = lane & 15, kq4 = lane >> 6 ? 0 : lane >> 4;  // kq4 = lane>>4 (0..3)
    kq4 = lane >> 4;
    int nb = blockIdx.x * 256 + w * 64;
    unsigned short* qbase = qa + ((size_t)(b * 4096 + nb)) * 512 + h * 64;
    const float* kvb = kv + (size_t)bh * 4096;
    v4f acc[4][4] = {};
    v4f accd[4] = {};
#pragma unroll
    for (int s = 0; s < 2; s++) {
        v8s af[4];
#pragma unroll
        for (int i = 0; i < 4; i++)
            af[i] = *(const v8s*)&qbase[(size_t)(i * 16 + mrow) * 512 + s * 32 + kq4 * 8];
        v8s nh, nl;
#pragma unroll
        for (int jj = 0; jj < 8; jj++) {
            float nv = fmaxf(ksum[bh * 64 + s * 32 + kq4 * 8 + jj], 100.0f);
            unsigned short hb = f2b(nv);
            nh[jj] = (short)hb;
            nl[jj] = (short)f2b(nv - b2f(hb));
        }
#pragma unroll
        for (int i = 0; i < 4; i++) {
            accd[i] = __builtin_amdgcn_mfma_f32_16x16x32_bf16(af[i], nh, accd[i], 0, 0, 0);
            accd[i] = __builtin_amdgcn_mfma_f32_16x16x32_bf16(af[i], nl, accd[i], 0, 0, 0);
        }
#pragma unroll
        for (int j = 0; j < 4; j++) {
            v8s kh, kl;
#pragma unroll
            for (int jj = 0; jj < 8; jj++) {
                float kvv = kvb[(size_t)(s * 32 + kq4 * 8 + jj) * 64 + j * 16 + mrow];
                unsigned short hb = f2b(kvv);
                kh[jj] = (short)hb;
                kl[jj] = (short)f2b(kvv - b2f(hb));
            }
#pragma unroll
            for (int i = 0; i < 4; i++) {
                acc[i][j] = __builtin_amdgcn_mfma_f32_16x16x32_bf16(af[i], kh, acc[i][j], 0, 0, 0);
                acc[i][j] = __builtin_amdgcn_mfma_f32_16x16x32_bf16(af[i], kl, acc[i][j], 0, 0, 0);
            }
        }
    }
    // per-row denom lives in the SAME lane/reg as the matching C rows
    unsigned short* ol = olds[w];
#pragma unroll
    for (int i = 0; i < 4; i++) {
        float inv[4];
#pragma unroll
        for (int r = 0; r < 4; r++) inv[r] = 1.0f / fmaxf(accd[i][r], 100.0f);
#pragma unroll
        for (int j = 0; j < 4; j++) {
            int dv = j * 16 + mrow;
#pragma unroll
            for (int r = 0; r < 4; r++) {
                int rl = i * 16 + kq4 * 4 + r;
                ol[rl * 64 + (((dv >> 3) ^ (rl & 7)) << 3) + (dv & 7)] = f2b(acc[i][j][r] * inv[r]);
            }
        }
    }
    __syncthreads();
#pragma unroll
    for (int p = 0; p < 8; p++) {
        int idx = p * 64 + lane;
        int row = idx >> 3, gl = idx & 7;
        v8s v = *(const v8s*)&ol[row * 64 + ((gl ^ (row & 7)) << 3)];
        *(v8s*)&qbase[(size_t)row * 512 + gl * 8] = v;
    }
}

// ---------------- fused LN2 + transpose: [B,N,C] bf16 -> LN -> [B,C,N] bf16 ----------
__global__ __launch_bounds__(256) void ln2_transpose(const unsigned short* __restrict__ in,
                                                     const float* __restrict__ g,
                                                     const float* __restrict__ bt,
                                                     unsigned short* __restrict__ out) {
    int bid = blockIdx.x;
    int b = bid >> 6;
    int n0 = (bid & 63) * 64;
    __shared__ float gs[512], bs[512];
    __shared__ __align__(16) unsigned short tile[512 * 64];
    int t = threadIdx.x;
    for (int i = t; i < 512; i += 256) { gs[i] = g[i]; bs[i] = bt[i]; }
    int nl = t >> 2, sub = t & 3;
    const unsigned short* src = in + ((size_t)(b * 4096 + n0 + nl)) * 512 + sub * 8;
    v8s vv[16];
#pragma unroll
    for (int c16 = 0; c16 < 16; c16++)
        vv[c16] = *(const v8s*)&src[c16 * 32];
    float s = 0.f, s2 = 0.f;
#pragma unroll
    for (int c16 = 0; c16 < 16; c16++)
#pragma unroll
        for (int j = 0; j < 8; j++) {
            float f = b2f((unsigned short)vv[c16][j]);
            s += f; s2 += f * f;
        }
    s += __shfl_xor(s, 1); s2 += __shfl_xor(s2, 1);
    s += __shfl_xor(s, 2); s2 += __shfl_xor(s2, 2);
    float mean = s * (1.f / 512.f);
    float var = s2 * (1.f / 512.f) - mean * mean;
    float inv = rsqrtf(var + 1e-5f);
    __syncthreads();
#pragma unroll
    for (int c16 = 0; c16 < 16; c16++) {
        int cb_ = sub * 8 + c16 * 32;
#pragma unroll
        for (int j = 0; j < 8; j++) {
            int c = cb_ + j;
            float f = b2f((unsigned short)vv[c16][j]);
            float y = (f - mean) * inv * gs[c] + bs[c];
            tile[c * 64 + ((((nl >> 3) ^ (c & 7)) << 3) | (nl & 7))] = f2b(y);
        }
    }
    __syncthreads();
    unsigned short* dst = out + ((size_t)b * 512) * 4096 + n0;
#pragma unroll
    for (int p = 0; p < 16; p++) {
        int chunk = p * 256 + t;
        int c = chunk >> 3, gseg = chunk & 7;
        int phys = gseg ^ (c & 7);
        v8s v = *(const v8s*)&tile[c * 64 + phys * 8];
        *(v8s*)&dst[(size_t)c * 4096 + gseg * 8] = v;
    }
}

// ---------------- depthwise conv 7x7 + GELU + BN stats; column-sliding ----------
__global__ __launch_bounds__(256) void dwconv7_gelu(const unsigned short* __restrict__ in,
                                                    const float* __restrict__ w,
                                                    const float* __restrict__ bias,
                                                    unsigned short* __restrict__ out,
                                                    float* __restrict__ bn_sum,
                                                    float* __restrict__ bn_sumsq) {
    int bc = blockIdx.x;
    int c = bc & 511;
    __shared__ float img[70 * 72];
    __shared__ float wsm[49];
    __shared__ float r1[4], r2[4];
    int t = threadIdx.x;
    int tx = t & 63, ty = t >> 6;
    for (int i = t; i < 70 * 72; i += 256) img[i] = 0.0f;
    if (t < 49) wsm[t] = w[c * 49 + t];
    __syncthreads();
    const unsigned short* src = in + (size_t)bc * 4096;
#pragma unroll
    for (int q = t; q < 512; q += 256) {
        v8s v = *(const v8s*)&src[q * 8];
        float* ip = &img[((q >> 3) + 3) * 72 + (q & 7) * 8 + 3];
#pragma unroll
        for (int j = 0; j < 8; j++) ip[j] = b2f((unsigned short)v[j]);
    }
    __syncthreads();
    float wt[49];
#pragma unroll
    for (int i = 0; i < 49; i++) wt[i] = wsm[i];
    float bv = bias[c];
    float acc[16];
#pragma unroll
    for (int i = 0; i < 16; i++) acc[i] = bv;
    int h0 = ty * 16;
#pragma unroll
    for (int rr = 0; rr < 22; rr++) {
        float v[7];
#pragma unroll
        for (int kw = 0; kw < 7; kw++) v[kw] = img[(h0 + rr) * 72 + tx + kw];
#pragma unroll
        for (int kh = 0; kh < 7; kh++) {
            int o = rr - kh;
            if (o >= 0 && o <= 15) {
                float dot = v[0] * wt[kh * 7];
#pragma unroll
                for (int kw = 1; kw < 7; kw++) dot += v[kw] * wt[kh * 7 + kw];
                acc[o] += dot;
            }
        }
    }
    float s = 0.0f, s2 = 0.0f;
    unsigned short* dst = out + (size_t)bc * 4096;
#pragma unroll
    for (int i = 0; i < 16; i++) {
        float a = acc[i];
        float ge = 0.5f * a * (1.0f + erff(a * 0.70710678118f));
        dst[(h0 + i) * 64 + tx] = f2b(ge);
        s += ge;
        s2 += ge * ge;
    }
    for (int o = 32; o > 0; o >>= 1) {
        s += __shfl_down(s, o);
        s2 += __shfl_down(s2, o);
    }
    int lane = t & 63;
    if (lane == 0) { r1[ty] = s; r2[ty] = s2; }
    __syncthreads();
    if (t == 0) {
        atomicAdd(&bn_sum[c], r1[0] + r1[1] + r1[2] + r1[3]);
        atomicAdd(&bn_sumsq[c], r2[0] + r2[1] + r2[2] + r2[3]);
    }
}

__global__ void bn_finalize(const float* __restrict__ s, const float* __restrict__ s2,
                            const float* __restrict__ g, const float* __restrict__ b,
                            float2* __restrict__ ab) {
    int c = blockIdx.x * blockDim.x + threadIdx.x;
    if (c >= 512) return;
    float m = s[c] * (1.0f / 32768.0f);
    float var = s2[c] * (1.0f / 32768.0f) - m * m;
    float inv = rsqrtf(var + 1e-5f);
    float sc = g[c] * inv;
    ab[c] = make_float2(sc, b[c] - m * sc);
}

// ---------------- depthwise conv 7x7 with BN affine on load; column-sliding -------------------
__global__ __launch_bounds__(256) void dwconv7_bn(const unsigned short* __restrict__ in,
                                                  const float2* __restrict__ bnab,
                                                  const float* __restrict__ w,
                                                  const float* __restrict__ bias,
                                                  unsigned short* __restrict__ out) {
    int bc = blockIdx.x;
    int c = bc & 511;
    __shared__ float img[70 * 72];
    __shared__ float wsm[49];
    int t = threadIdx.x;
    int tx = t & 63, ty = t >> 6;
    for (int i = t; i < 70 * 72; i += 256) img[i] = 0.0f;
    if (t < 49) wsm[t] = w[c * 49 + t];
    __syncthreads();
    float2 ab = bnab[c];
    const unsigned short* src = in + (size_t)bc * 4096;
#pragma unroll
    for (int q = t; q < 512; q += 256) {
        v8s v = *(const v8s*)&src[q * 8];
        float* ip = &img[((q >> 3) + 3) * 72 + (q & 7) * 8 + 3];
#pragma unroll
        for (int j = 0; j < 8; j++) ip[j] = b2f((unsigned short)v[j]) * ab.x + ab.y;
    }
    __syncthreads();
    float wt[49];
#pragma unroll
    for (int i = 0; i < 49; i++) wt[i] = wsm[i];
    float bv = bias[c];
    float acc[16];
#pragma unroll
    for (int i = 0; i < 16; i++) acc[i] = bv;
    int h0 = ty * 16;
#pragma unroll
    for (int rr = 0; rr < 22; rr++) {
        float v[7];
#pragma unroll
        for (int kw = 0; kw < 7; kw++) v[kw] = img[(h0 + rr) * 72 + tx + kw];
#pragma unroll
        for (int kh = 0; kh < 7; kh++) {
            int o = rr - kh;
            if (o >= 0 && o <= 15) {
                float dot = v[0] * wt[kh * 7];
#pragma unroll
                for (int kw = 1; kw < 7; kw++) dot += v[kw] * wt[kh * 7 + kw];
                acc[o] += dot;
            }
        }
    }
    unsigned short* dst = out + (size_t)bc * 4096;
#pragma unroll
    for (int i = 0; i < 16; i++)
        dst[(h0 + i) * 64 + tx] = f2b(acc[i]);
}

// ---------------- final: out = x(f32) + attn(bf16) + y2^T(bf16) -> f32 (vectorized) -----------
__global__ __launch_bounds__(256) void final_add(const float* __restrict__ x,
                                                 const unsigned short* __restrict__ attn,
                                                 const unsigned short* __restrict__ y2,
                                                 float* __restrict__ out) {
    __shared__ unsigned short tile[32][36];
    int b = blockIdx.z;
    int c0 = blockIdx.x * 32, n0 = blockIdx.y * 32;
    int t = threadIdx.x;
    {
        int c = t >> 3, n4 = (t & 7) * 4;
        ushort4 v = *(const ushort4*)&y2[((size_t)(b * 512 + c0 + c)) * 4096 + n0 + n4];
        tile[c][n4] = v.x; tile[c][n4 + 1] = v.y; tile[c][n4 + 2] = v.z; tile[c][n4 + 3] = v.w;
    }
    __syncthreads();
    int nl = t >> 3, cl = (t & 7) * 4;
    size_t idx = ((size_t)(b * 4096 + n0 + nl)) * 512 + c0 + cl;
    float4 xv = *(const float4*)&x[idx];
    ushort4 av = *(const ushort4*)&attn[idx];
    float4 o;
    o.x = xv.x + b2f(av.x) + b2f(tile[cl][nl]);
    o.y = xv.y + b2f(av.y) + b2f(tile[cl + 1][nl]);
    o.z = xv.z + b2f(av.z) + b2f(tile[cl + 2][nl]);
    o.w = xv.w + b2f(av.w) + b2f(tile[cl + 3][nl]);
    *(float4*)&out[idx] = o;
}

// ------------------------------------------------------------------------------------------------
extern "C" void kernel_launch(void* const* d_in, const int* in_sizes, int n_in,
                              void* d_out, int out_size, void* d_ws, size_t ws_size,
                              hipStream_t stream) {
    const float* x     = (const float*)d_in[0];
    const float* qkv_w = (const float*)d_in[1];
    const float* qkv_b = (const float*)d_in[2];
    const float* out_w = (const float*)d_in[3];
    const float* out_b = (const float*)d_in[4];
    const float* pre_g = (const float*)d_in[5];
    const float* pre_b = (const float*)d_in[6];
    const float* lcm_g = (const float*)d_in[7];
    const float* lcm_b = (const float*)d_in[8];
    const float* ci_w  = (const float*)d_in[9];
    const float* ci_b  = (const float*)d_in[10];
    const float* bn_g  = (const float*)d_in[11];
    const float* bn_b  = (const float*)d_in[12];
    const float* co_w  = (const float*)d_in[13];
    const float* co_b  = (const float*)d_in[14];

    char* ws = (char*)d_ws;
    const size_t SLOT = 33554432;  // 32768*512*2 bytes (bf16)
    unsigned short* S0 = (unsigned short*)(ws);               // q -> attn -> xi -> y2
    unsigned short* S1 = (unsigned short*)(ws + SLOT);        // kT -> attn_out(bf16)
    unsigned short* S2 = (unsigned short*)(ws + 2 * SLOT);    // vT -> y
    const size_t MISC = 3 * SLOT;                             // 96MB
    unsigned short* wT1 = (unsigned short*)(ws + MISC);                 // 1.5MB bf16
    unsigned short* wT2 = (unsigned short*)(ws + MISC + 1572864);       // 0.5MB bf16
    float* kvb          = (float*)(ws + MISC + 2097152);                // 1MB
    float* ksum         = (float*)(ws + MISC + 2097152 + 1048576);      // 16KB
    float* bn_sum       = (float*)(ws + MISC + 2097152 + 1048576 + 16384);        // 2KB
    float* bn_sumsq     = (float*)(ws + MISC + 2097152 + 1048576 + 16384 + 2048); // 2KB
    float2* bnab        = (float2*)(ws + MISC + 3166208);               // 4KB
    float* ksp          = (float*)(ws + MISC + 3170304);                // 512KB (uses 128KB)
    float* outp         = (float*)d_out;

    // d_out doubles as scratch before final_add fully overwrites it:
    unsigned short* normed = (unsigned short*)d_out;                    // 32MB bf16
    float* kvp             = (float*)((char*)d_out + SLOT);             // 8MB fp32 partials

    dim3 tb(32, 8);
    transpose_f2b<<<dim3(48, 16), tb, 0, stream>>>(qkv_w, wT1, 512, 1536);
    transpose_f2b<<<dim3(16, 16), tb, 0, stream>>>(out_w, wT2, 512, 512);
    zero_fill<<<4, 256, 0, stream>>>(bn_sum, 1024);  // bn_sum + bn_sumsq
    ln_apply<<<32768, 256, 0, stream>>>(x, pre_g, pre_b, normed);
    // M=32768/256=128, N=1536/128=12 -> 1536 blocks (%8==0); writes q + kT + vT
    gemm256<12, true><<<1536, 512, 0, stream>>>(normed, wT1, qkv_b, S0, S1, S2);
    kv_part<<<dim3(64, 8), 256, 0, stream>>>(S1, S2, kvp, ksp);
    kv_reduce<<<1024, 256, 0, stream>>>(kvp, ksp, kvb, ksum);
    attn_mfma<<<dim3(16, 64), 256, 0, stream>>>(S0, kvb, ksum);
    // M=128, N=512/128=4 -> 512 blocks (%8==0)
    gemm256<4, false><<<512, 512, 0, stream>>>(S0, wT2, out_b, S1, S1, S1);
    // fused LN2 + transpose: S1 [B,N,C] -> S0 [B,C,N]
    ln2_transpose<<<512, 256, 0, stream>>>(S1, lcm_g, lcm_b, S0);
    dwconv7_gelu<<<4096, 256, 0, stream>>>(S0, ci_w, ci_b, S2, bn_sum, bn_sumsq);
    bn_finalize<<<2, 256, 0, stream>>>(bn_sum, bn_sumsq, bn_g, bn_b, bnab);
    dwconv7_bn<<<4096, 256, 0, stream>>>(S2, bnab, co_w, co_b, S0);
    final_add<<<dim3(16, 128, 8), tb.x * tb.y, 0, stream>>>(x, S1, S0, outp);
}

// Round 5
// 419.905 us; speedup vs baseline: 1.2358x; 1.0395x over previous
//
#include <hip/hip_runtime.h>
#include <math.h>

typedef short v8s __attribute__((ext_vector_type(8)));
typedef short v4s __attribute__((ext_vector_type(4)));
typedef float v4f __attribute__((ext_vector_type(4)));

__device__ __forceinline__ float b2f(unsigned short u) {
    return __uint_as_float(((unsigned)u) << 16);
}
__device__ __forceinline__ unsigned short f2b(float f) {
    unsigned u = __float_as_uint(f);
    unsigned r = (u + 0x7FFF + ((u >> 16) & 1)) >> 16;
    return (unsigned short)r;
}
__device__ __forceinline__ int swz8(int row) { return (row & 7) ^ ((row >> 3) & 7); }

// async global->LDS, 16B per lane; lds dest is wave-uniform base + lane*16
__device__ __forceinline__ void gl_lds16(const unsigned short* g, unsigned short* l) {
    __builtin_amdgcn_global_load_lds(
        (const __attribute__((address_space(1))) void*)g,
        (__attribute__((address_space(3))) void*)l,
        16, 0, 0);
}

// ---------------- zero fill ----------------
__global__ __launch_bounds__(256) void zero_fill(float* __restrict__ p, int n) {
    int i = blockIdx.x * 256 + threadIdx.x;
    if (i < n) p[i] = 0.0f;
}

// ---------------- LN1: fp32 x -> bf16 normed; wave-per-row, no LDS ----------------
__global__ __launch_bounds__(256) void ln_apply(const float* __restrict__ x,
                                                const float* __restrict__ g,
                                                const float* __restrict__ bt,
                                                unsigned short* __restrict__ out) {
    int t = threadIdx.x;
    int lane = t & 63, wave = t >> 6;
    size_t row = (size_t)blockIdx.x * 4 + wave;
    const float* p = x + row * 512 + lane * 8;
    float4 va = *(const float4*)p;
    float4 vb = *(const float4*)(p + 4);
    float s = va.x + va.y + va.z + va.w + vb.x + vb.y + vb.z + vb.w;
    float s2 = va.x * va.x + va.y * va.y + va.z * va.z + va.w * va.w +
               vb.x * vb.x + vb.y * vb.y + vb.z * vb.z + vb.w * vb.w;
    for (int o = 32; o > 0; o >>= 1) {
        s += __shfl_xor(s, o);
        s2 += __shfl_xor(s2, o);
    }
    float mean = s * (1.0f / 512.0f);
    float var = s2 * (1.0f / 512.0f) - mean * mean;
    float inv = rsqrtf(var + 1e-5f);
    float4 g0 = *(const float4*)(g + lane * 8);
    float4 g1 = *(const float4*)(g + lane * 8 + 4);
    float4 b0 = *(const float4*)(bt + lane * 8);
    float4 b1 = *(const float4*)(bt + lane * 8 + 4);
    v8s o8;
    o8[0] = (short)f2b((va.x - mean) * inv * g0.x + b0.x);
    o8[1] = (short)f2b((va.y - mean) * inv * g0.y + b0.y);
    o8[2] = (short)f2b((va.z - mean) * inv * g0.z + b0.z);
    o8[3] = (short)f2b((va.w - mean) * inv * g0.w + b0.w);
    o8[4] = (short)f2b((vb.x - mean) * inv * g1.x + b1.x);
    o8[5] = (short)f2b((vb.y - mean) * inv * g1.y + b1.y);
    o8[6] = (short)f2b((vb.z - mean) * inv * g1.z + b1.z);
    o8[7] = (short)f2b((vb.w - mean) * inv * g1.w + b1.w);
    *(v8s*)&out[row * 512 + lane * 8] = o8;
}

// ---------------- weight transpose + fp32->bf16 ----------------
__global__ __launch_bounds__(256) void transpose_f2b(const float* __restrict__ in,
                                                     unsigned short* __restrict__ out,
                                                     int R, int C) {
    __shared__ unsigned short tile[32][33];
    int c0 = blockIdx.x * 32, r0 = blockIdx.y * 32;
    int tx = threadIdx.x, ty = threadIdx.y;
    for (int j = 0; j < 32; j += 8)
        tile[ty + j][tx] = f2b(in[(size_t)(r0 + ty + j) * C + c0 + tx]);
    __syncthreads();
    for (int j = 0; j < 32; j += 8)
        out[(size_t)(c0 + ty + j) * R + r0 + tx] = tile[tx][ty + j];
}

// ================================================================================
// 256x128-tile GEMM, K=512 (16 K-tiles of BK=32), 8 waves (4Mx2N), 512 threads.
// 3-slot LDS K-tile ring (72KB -> 2 blocks/CU) with counted vmcnt AND
// register-level fragment double-buffering (r5):
//   per tile kt: barrierA; STAGE(kt+2); MFMA half1(kt); vmcnt(3) [retires kt+1:
//   outstanding = {kt+1:3, kt+2:3}]; barrierB [all waves' kt+1 loads in LDS];
//   ds_read frags(kt+1) -> regs; MFMA half2(kt).  Frag reads complete under
//   half2 + barrierA + STAGE of the next tile -> ds_read latency hidden.
// T2 both-sides granule swizzle; T1 bijective XCD swizzle; T5 setprio.
// Epilogue: C tile staged in LDS (stride 136, swizzled); q/gemm2 coalesced
// row-major; k,v written TRANSPOSED as kT/vT [bh][d][n] for MFMA consumers.
// ================================================================================
template <int NB, bool QKV>
__global__ __launch_bounds__(512, 4) void gemm256(const unsigned short* __restrict__ A,
                                                  const unsigned short* __restrict__ Bt,
                                                  const float* __restrict__ bias,
                                                  unsigned short* __restrict__ o0,
                                                  unsigned short* __restrict__ o1,
                                                  unsigned short* __restrict__ o2) {
    __shared__ __align__(16) unsigned short LB[3][12288];  // slot: A[0..8191], B[8192..12287]
    int t = threadIdx.x;
    int wave = t >> 6, lane = t & 63;
    int wm = wave >> 1, wn = wave & 1;           // 4 M-quarters x 2 N-halves
    int mrow = lane & 15, kq4 = lane >> 4;
    int nwg = gridDim.x;
    int cpx = nwg >> 3;
    int bid = blockIdx.x;
    int swz = (bid & 7) * cpx + (bid >> 3);
    int n0 = (swz % NB) * 128;
    int m0 = (swz / NB) * 256;
    const unsigned short* Ab = A + (size_t)m0 * 512;
    const unsigned short* Bb = Bt + (size_t)n0 * 512;
    int rA0 = t >> 2;
    int cA0 = (((t & 3) ^ ((rA0 >> 1) & 3)) * 8);
    int rA1 = 128 + (t >> 2);
    int cA1 = (((t & 3) ^ ((rA1 >> 1) & 3)) * 8);
    size_t srcA0 = (size_t)rA0 * 512 + cA0;
    size_t srcA1 = (size_t)rA1 * 512 + cA1;
    unsigned offA0 = wave * 512;
    unsigned offA1 = 4096 + wave * 512;
    unsigned offB  = 8192 + wave * 512;
    v4f acc[4][4] = {};
    int swr = ((kq4 ^ ((mrow >> 1) & 3)) * 8);

#define STAGE(kt, slot)                                          \
    do {                                                         \
        const unsigned short* aS = Ab + (size_t)(kt) * 32;       \
        const unsigned short* bS = Bb + (size_t)(kt) * 32;       \
        gl_lds16(aS + srcA0, &LB[slot][offA0]);                  \
        gl_lds16(aS + srcA1, &LB[slot][offA1]);                  \
        gl_lds16(bS + srcA0, &LB[slot][offB]);                   \
    } while (0)

    STAGE(0, 0);
    STAGE(1, 1);
    asm volatile("s_waitcnt vmcnt(3)" ::: "memory");
    __builtin_amdgcn_s_barrier();
    asm volatile("" ::: "memory");
    v8s cA[4], cB[4];
    {
        const unsigned short* as = LB[0];
        const unsigned short* bs = as + 8192;
#pragma unroll
        for (int i = 0; i < 4; i++) {
            cA[i] = *(const v8s*)&as[(wm * 64 + i * 16 + mrow) * 32 + swr];
            cB[i] = *(const v8s*)&bs[(wn * 64 + i * 16 + mrow) * 32 + swr];
        }
    }
#pragma unroll
    for (int kt = 0; kt < 16; ++kt) {
        __builtin_amdgcn_s_barrier();
        asm volatile("" ::: "memory");
        if (kt + 2 < 16) STAGE(kt + 2, (kt + 2) % 3);
        __builtin_amdgcn_s_setprio(1);
#pragma unroll
        for (int i = 0; i < 2; i++)
#pragma unroll
            for (int j = 0; j < 4; j++)
                acc[i][j] = __builtin_amdgcn_mfma_f32_16x16x32_bf16(cA[i], cB[j], acc[i][j], 0, 0, 0);
        v8s nA[4], nB[4];
        if (kt < 15) {
            if (kt < 14) {
                asm volatile("s_waitcnt vmcnt(3)" ::: "memory");
            } else {
                asm volatile("s_waitcnt vmcnt(0)" ::: "memory");
            }
            __builtin_amdgcn_s_barrier();
            asm volatile("" ::: "memory");
            const unsigned short* as = LB[(kt + 1) % 3];
            const unsigned short* bs = as + 8192;
#pragma unroll
            for (int i = 0; i < 4; i++) {
                nA[i] = *(const v8s*)&as[(wm * 64 + i * 16 + mrow) * 32 + swr];
                nB[i] = *(const v8s*)&bs[(wn * 64 + i * 16 + mrow) * 32 + swr];
            }
        }
#pragma unroll
        for (int i = 2; i < 4; i++)
#pragma unroll
            for (int j = 0; j < 4; j++)
                acc[i][j] = __builtin_amdgcn_mfma_f32_16x16x32_bf16(cA[i], cB[j], acc[i][j], 0, 0, 0);
        __builtin_amdgcn_s_setprio(0);
        if (kt < 15) {
#pragma unroll
            for (int i = 0; i < 4; i++) { cA[i] = nA[i]; cB[i] = nB[i]; }
        }
    }
#undef STAGE
    // ---------------- epilogue: stage C tile in LDS (stride 136, swizzled) ----------
    __syncthreads();
    unsigned short* CT = &LB[0][0];  // 256 rows x 128 cols, stride 136 shorts
    bool doRelu = QKV && (n0 < 1024);
#pragma unroll
    for (int j = 0; j < 4; j++) {
        int col = wn * 64 + j * 16 + mrow;          // tile-local col 0..127
        float bv = bias[n0 + col];
        int gr = col >> 3, gb = col & 7;
#pragma unroll
        for (int i = 0; i < 4; i++) {
            int rowb = wm * 64 + i * 16 + kq4 * 4;
#pragma unroll
            for (int r = 0; r < 4; r++) {
                int row = rowb + r;
                float v = acc[i][j][r] + bv;
                if (doRelu) v = fmaxf(v, 0.0f);
                CT[row * 136 + ((gr ^ swz8(row)) << 3) + gb] = f2b(v);
            }
        }
    }
    __syncthreads();
    if (!QKV || n0 < 512) {
        // coalesced row-major write (q / gemm2 out)
#pragma unroll
        for (int p = 0; p < 8; p++) {
            int g = p * 512 + t;
            int row = g >> 4, gl = g & 15;
            v8s v = *(const v8s*)&CT[row * 136 + ((gl ^ swz8(row)) << 3)];
            *(v8s*)&o0[(size_t)(m0 + row) * 512 + n0 + gl * 8] = v;
        }
    } else {
        // transposed write: kT (512<=col<1024) or vT (>=1024), layout [bh][d][n]
        unsigned short* Tb = (n0 < 1024) ? o1 : o2;
        int col = t >> 2, sub = t & 3;
        int cglob = n0 + col;
        int hl = (cglob & 511) >> 6, d = cglob & 63;
        int bb = m0 >> 12, gc = m0 & 4095;
        unsigned short* dst = Tb + ((size_t)((bb * 8 + hl) * 64 + d)) * 4096 + gc;
        int cg = col >> 3, cb7 = col & 7;
#pragma unroll
        for (int g = 0; g < 8; g++) {
            v8s v;
#pragma unroll
            for (int e = 0; e < 8; e++) {
                int rr = g * 32 + sub * 8 + e;
                v[e] = (short)CT[rr * 136 + ((cg ^ swz8(rr)) << 3) + cb7];
            }
            *(v8s*)&dst[g * 32 + sub * 8] = v;
        }
    }
}

// ---------------- kv partials via MFMA: KV[dk][dv] = sum_n kT[dk][n]*vT[dv][n] --------
__global__ __launch_bounds__(256) void kv_part(const unsigned short* __restrict__ kT,
                                               const unsigned short* __restrict__ vT,
                                               float* __restrict__ kvp,
                                               float* __restrict__ ksp) {
    __shared__ __align__(16) unsigned short LB[3][4096];  // slot: K 2048 + V 2048 shorts
    int bh = blockIdx.x, nc = blockIdx.y;
    int t = threadIdx.x;
    int w = t >> 6, lane = t & 63;
    int wdk = w >> 1, wdv = w & 1;
    int mrow = lane & 15, kq4 = lane >> 4;
    const unsigned short* Kb = kT + (size_t)bh * 262144 + nc * 512;
    const unsigned short* Vb = vT + (size_t)bh * 262144 + nc * 512;
    int rA = t >> 2;
    int lcA = (t & 3) ^ (rA & 3);
    size_t srcoff = (size_t)rA * 4096 + lcA * 8;
    unsigned dstK = w * 512;
    unsigned dstV = 2048 + w * 512;
    v4f acc[2][2] = {};
    v4f accs[2] = {};
    v8s ones;
#pragma unroll
    for (int jj = 0; jj < 8; jj++) ones[jj] = (short)0x3F80;

#define KSTAGE(ks, slot)                                         \
    do {                                                         \
        gl_lds16(Kb + (size_t)(ks) * 32 + srcoff, &LB[slot][dstK]); \
        gl_lds16(Vb + (size_t)(ks) * 32 + srcoff, &LB[slot][dstV]); \
    } while (0)

    KSTAGE(0, 0);
    KSTAGE(1, 1);
    for (int ks = 0; ks < 16; ++ks) {
        if (ks < 15) {
            asm volatile("s_waitcnt vmcnt(2)" ::: "memory");
        } else {
            asm volatile("s_waitcnt vmcnt(0)" ::: "memory");
        }
        __builtin_amdgcn_s_barrier();
        asm volatile("" ::: "memory");
        if (ks + 2 < 16) KSTAGE(ks + 2, (ks + 2) % 3);
        const unsigned short* as = LB[ks % 3];
        v8s af[2], bf[2];
#pragma unroll
        for (int i = 0; i < 2; i++) {
            int row = wdk * 32 + i * 16 + mrow;
            af[i] = *(const v8s*)&as[row * 32 + ((kq4 ^ (row & 3)) << 3)];
        }
#pragma unroll
        for (int j = 0; j < 2; j++) {
            int row = wdv * 32 + j * 16 + mrow;
            bf[j] = *(const v8s*)&as[2048 + row * 32 + ((kq4 ^ (row & 3)) << 3)];
        }
#pragma unroll
        for (int i = 0; i < 2; i++)
#pragma unroll
            for (int j = 0; j < 2; j++)
                acc[i][j] = __builtin_amdgcn_mfma_f32_16x16x32_bf16(af[i], bf[j], acc[i][j], 0, 0, 0);
        if (wdv == 0) {
#pragma unroll
            for (int i = 0; i < 2; i++)
                accs[i] = __builtin_amdgcn_mfma_f32_16x16x32_bf16(af[i], ones, accs[i], 0, 0, 0);
        }
    }
#undef KSTAGE
    float* dst = kvp + ((size_t)(bh * 8 + nc)) * 4096;
#pragma unroll
    for (int i = 0; i < 2; i++)
#pragma unroll
        for (int j = 0; j < 2; j++)
#pragma unroll
            for (int r = 0; r < 4; r++) {
                int row = wdk * 32 + i * 16 + kq4 * 4 + r;
                int col = wdv * 32 + j * 16 + mrow;
                dst[row * 64 + col] = acc[i][j][r];
            }
    if (wdv == 0 && mrow == 0) {
        float* kd = ksp + ((size_t)(bh * 8 + nc)) * 64 + wdk * 32;
#pragma unroll
        for (int i = 0; i < 2; i++)
#pragma unroll
            for (int r = 0; r < 4; r++)
                kd[i * 16 + kq4 * 4 + r] = accs[i][r];
    }
}

// ---------------- kv reduce: sum 8 partials -> bf16 hi/lo planes + nrm planes --------
// kvhT/kvlT layout [bh][dv][dk] (transposed for attn's B-fragment v8s loads);
// nrmp layout [bh][2][64] = {hi, lo} of clamp(ksum, 100).
__global__ __launch_bounds__(256) void kv_reduce(const float* __restrict__ kvp,
                                                 const float* __restrict__ ksp,
                                                 unsigned short* __restrict__ kvhT,
                                                 unsigned short* __restrict__ kvlT,
                                                 unsigned short* __restrict__ nrmp) {
    int tid = blockIdx.x * 256 + threadIdx.x;
    int bh = tid >> 12, e = tid & 4095;
    int dk = e >> 6, dv = e & 63;
    float s = 0.0f;
#pragma unroll
    for (int c = 0; c < 8; c++) s += kvp[((size_t)(bh * 8 + c)) * 4096 + e];
    unsigned short hb = f2b(s);
    kvhT[(size_t)bh * 4096 + dv * 64 + dk] = hb;
    kvlT[(size_t)bh * 4096 + dv * 64 + dk] = f2b(s - b2f(hb));
    if (tid < 4096) {
        int bh2 = tid >> 6, dk2 = tid & 63;
        float x = 0.0f;
#pragma unroll
        for (int c = 0; c < 8; c++) x += ksp[(bh2 * 8 + c) * 64 + dk2];
        x = fmaxf(x, 100.0f);
        unsigned short nh = f2b(x);
        nrmp[bh2 * 128 + dk2] = nh;
        nrmp[bh2 * 128 + 64 + dk2] = f2b(x - b2f(nh));
    }
}

// ---------------- attn via MFMA; IN-PLACE over q; pre-split bf16 planes -------------
__global__ __launch_bounds__(256) void attn_mfma(unsigned short* __restrict__ qa,
                                                 const unsigned short* __restrict__ kvhT,
                                                 const unsigned short* __restrict__ kvlT,
                                                 const unsigned short* __restrict__ nrmp) {
    __shared__ __align__(16) unsigned short olds[4][4096];
    int bh = blockIdx.y;
    int b = bh >> 3, h = bh & 7;
    int t = threadIdx.x;
    int w = t >> 6, lane = t & 63;
    int mrow = lane & 15, kq4 = lane >> 4;
    int nb = blockIdx.x * 256 + w * 64;
    unsigned short* qbase = qa + ((size_t)(b * 4096 + nb)) * 512 + h * 64;
    v4f acc[4][4] = {};
    v4f accd[4] = {};
#pragma unroll
    for (int s = 0; s < 2; s++) {
        v8s af[4];
#pragma unroll
        for (int i = 0; i < 4; i++)
            af[i] = *(const v8s*)&qbase[(size_t)(i * 16 + mrow) * 512 + s * 32 + kq4 * 8];
        v8s nh = *(const v8s*)&nrmp[bh * 128 + s * 32 + kq4 * 8];
        v8s nl = *(const v8s*)&nrmp[bh * 128 + 64 + s * 32 + kq4 * 8];
#pragma unroll
        for (int i = 0; i < 4; i++) {
            accd[i] = __builtin_amdgcn_mfma_f32_16x16x32_bf16(af[i], nh, accd[i], 0, 0, 0);
            accd[i] = __builtin_amdgcn_mfma_f32_16x16x32_bf16(af[i], nl, accd[i], 0, 0, 0);
        }
#pragma unroll
        for (int j = 0; j < 4; j++) {
            v8s kh = *(const v8s*)&kvhT[(size_t)bh * 4096 + (j * 16 + mrow) * 64 + s * 32 + kq4 * 8];
            v8s kl = *(const v8s*)&kvlT[(size_t)bh * 4096 + (j * 16 + mrow) * 64 + s * 32 + kq4 * 8];
#pragma unroll
            for (int i = 0; i < 4; i++) {
                acc[i][j] = __builtin_amdgcn_mfma_f32_16x16x32_bf16(af[i], kh, acc[i][j], 0, 0, 0);
                acc[i][j] = __builtin_amdgcn_mfma_f32_16x16x32_bf16(af[i], kl, acc[i][j], 0, 0, 0);
            }
        }
    }
    // per-row denom lives in the SAME lane/reg as the matching C rows
    unsigned short* ol = olds[w];
#pragma unroll
    for (int i = 0; i < 4; i++) {
        float inv[4];
#pragma unroll
        for (int r = 0; r < 4; r++) inv[r] = 1.0f / fmaxf(accd[i][r], 100.0f);
#pragma unroll
        for (int j = 0; j < 4; j++) {
            int dv = j * 16 + mrow;
#pragma unroll
            for (int r = 0; r < 4; r++) {
                int rl = i * 16 + kq4 * 4 + r;
                ol[rl * 64 + (((dv >> 3) ^ (rl & 7)) << 3) + (dv & 7)] = f2b(acc[i][j][r] * inv[r]);
            }
        }
    }
    __syncthreads();
#pragma unroll
    for (int p = 0; p < 8; p++) {
        int idx = p * 64 + lane;
        int row = idx >> 3, gl = idx & 7;
        v8s v = *(const v8s*)&ol[row * 64 + ((gl ^ (row & 7)) << 3)];
        *(v8s*)&qbase[(size_t)row * 512 + gl * 8] = v;
    }
}

// ---------------- fused LN2 + transpose: [B,N,C] bf16 -> LN -> [B,C,N] bf16 ----------
__global__ __launch_bounds__(256) void ln2_transpose(const unsigned short* __restrict__ in,
                                                     const float* __restrict__ g,
                                                     const float* __restrict__ bt,
                                                     unsigned short* __restrict__ out) {
    int bid = blockIdx.x;
    int b = bid >> 6;
    int n0 = (bid & 63) * 64;
    __shared__ float gs[512], bs[512];
    __shared__ __align__(16) unsigned short tile[512 * 64];
    int t = threadIdx.x;
    for (int i = t; i < 512; i += 256) { gs[i] = g[i]; bs[i] = bt[i]; }
    int nl = t >> 2, sub = t & 3;
    const unsigned short* src = in + ((size_t)(b * 4096 + n0 + nl)) * 512 + sub * 8;
    v8s vv[16];
#pragma unroll
    for (int c16 = 0; c16 < 16; c16++)
        vv[c16] = *(const v8s*)&src[c16 * 32];
    float s = 0.f, s2 = 0.f;
#pragma unroll
    for (int c16 = 0; c16 < 16; c16++)
#pragma unroll
        for (int j = 0; j < 8; j++) {
            float f = b2f((unsigned short)vv[c16][j]);
            s += f; s2 += f * f;
        }
    s += __shfl_xor(s, 1); s2 += __shfl_xor(s2, 1);
    s += __shfl_xor(s, 2); s2 += __shfl_xor(s2, 2);
    float mean = s * (1.f / 512.f);
    float var = s2 * (1.f / 512.f) - mean * mean;
    float inv = rsqrtf(var + 1e-5f);
    __syncthreads();
#pragma unroll
    for (int c16 = 0; c16 < 16; c16++) {
        int cb_ = sub * 8 + c16 * 32;
#pragma unroll
        for (int j = 0; j < 8; j++) {
            int c = cb_ + j;
            float f = b2f((unsigned short)vv[c16][j]);
            float y = (f - mean) * inv * gs[c] + bs[c];
            tile[c * 64 + ((((nl >> 3) ^ (c & 7)) << 3) | (nl & 7))] = f2b(y);
        }
    }
    __syncthreads();
    unsigned short* dst = out + ((size_t)b * 512) * 4096 + n0;
#pragma unroll
    for (int p = 0; p < 16; p++) {
        int chunk = p * 256 + t;
        int c = chunk >> 3, gseg = chunk & 7;
        int phys = gseg ^ (c & 7);
        v8s v = *(const v8s*)&tile[c * 64 + phys * 8];
        *(v8s*)&dst[(size_t)c * 4096 + gseg * 8] = v;
    }
}

// ---------------- depthwise conv 7x7 + GELU + BN stats; column-sliding ----------
__global__ __launch_bounds__(256) void dwconv7_gelu(const unsigned short* __restrict__ in,
                                                    const float* __restrict__ w,
                                                    const float* __restrict__ bias,
                                                    unsigned short* __restrict__ out,
                                                    float* __restrict__ bn_sum,
                                                    float* __restrict__ bn_sumsq) {
    int bc = blockIdx.x;
    int c = bc & 511;
    __shared__ float img[70 * 72];
    __shared__ float wsm[49];
    __shared__ float r1[4], r2[4];
    int t = threadIdx.x;
    int tx = t & 63, ty = t >> 6;
    for (int i = t; i < 70 * 72; i += 256) img[i] = 0.0f;
    if (t < 49) wsm[t] = w[c * 49 + t];
    __syncthreads();
    const unsigned short* src = in + (size_t)bc * 4096;
#pragma unroll
    for (int q = t; q < 512; q += 256) {
        v8s v = *(const v8s*)&src[q * 8];
        float* ip = &img[((q >> 3) + 3) * 72 + (q & 7) * 8 + 3];
#pragma unroll
        for (int j = 0; j < 8; j++) ip[j] = b2f((unsigned short)v[j]);
    }
    __syncthreads();
    float wt[49];
#pragma unroll
    for (int i = 0; i < 49; i++) wt[i] = wsm[i];
    float bv = bias[c];
    float acc[16];
#pragma unroll
    for (int i = 0; i < 16; i++) acc[i] = bv;
    int h0 = ty * 16;
#pragma unroll
    for (int rr = 0; rr < 22; rr++) {
        float v[7];
#pragma unroll
        for (int kw = 0; kw < 7; kw++) v[kw] = img[(h0 + rr) * 72 + tx + kw];
#pragma unroll
        for (int kh = 0; kh < 7; kh++) {
            int o = rr - kh;
            if (o >= 0 && o <= 15) {
                float dot = v[0] * wt[kh * 7];
#pragma unroll
                for (int kw = 1; kw < 7; kw++) dot += v[kw] * wt[kh * 7 + kw];
                acc[o] += dot;
            }
        }
    }
    float s = 0.0f, s2 = 0.0f;
    unsigned short* dst = out + (size_t)bc * 4096;
#pragma unroll
    for (int i = 0; i < 16; i++) {
        float a = acc[i];
        float ge = 0.5f * a * (1.0f + erff(a * 0.70710678118f));
        dst[(h0 + i) * 64 + tx] = f2b(ge);
        s += ge;
        s2 += ge * ge;
    }
    for (int o = 32; o > 0; o >>= 1) {
        s += __shfl_down(s, o);
        s2 += __shfl_down(s2, o);
    }
    int lane = t & 63;
    if (lane == 0) { r1[ty] = s; r2[ty] = s2; }
    __syncthreads();
    if (t == 0) {
        atomicAdd(&bn_sum[c], r1[0] + r1[1] + r1[2] + r1[3]);
        atomicAdd(&bn_sumsq[c], r2[0] + r2[1] + r2[2] + r2[3]);
    }
}

__global__ void bn_finalize(const float* __restrict__ s, const float* __restrict__ s2,
                            const float* __restrict__ g, const float* __restrict__ b,
                            float2* __restrict__ ab) {
    int c = blockIdx.x * blockDim.x + threadIdx.x;
    if (c >= 512) return;
    float m = s[c] * (1.0f / 32768.0f);
    float var = s2[c] * (1.0f / 32768.0f) - m * m;
    float inv = rsqrtf(var + 1e-5f);
    float sc = g[c] * inv;
    ab[c] = make_float2(sc, b[c] - m * sc);
}

// ---------------- depthwise conv 7x7 with BN affine on load; column-sliding -------------------
__global__ __launch_bounds__(256) void dwconv7_bn(const unsigned short* __restrict__ in,
                                                  const float2* __restrict__ bnab,
                                                  const float* __restrict__ w,
                                                  const float* __restrict__ bias,
                                                  unsigned short* __restrict__ out) {
    int bc = blockIdx.x;
    int c = bc & 511;
    __shared__ float img[70 * 72];
    __shared__ float wsm[49];
    int t = threadIdx.x;
    int tx = t & 63, ty = t >> 6;
    for (int i = t; i < 70 * 72; i += 256) img[i] = 0.0f;
    if (t < 49) wsm[t] = w[c * 49 + t];
    __syncthreads();
    float2 ab = bnab[c];
    const unsigned short* src = in + (size_t)bc * 4096;
#pragma unroll
    for (int q = t; q < 512; q += 256) {
        v8s v = *(const v8s*)&src[q * 8];
        float* ip = &img[((q >> 3) + 3) * 72 + (q & 7) * 8 + 3];
#pragma unroll
        for (int j = 0; j < 8; j++) ip[j] = b2f((unsigned short)v[j]) * ab.x + ab.y;
    }
    __syncthreads();
    float wt[49];
#pragma unroll
    for (int i = 0; i < 49; i++) wt[i] = wsm[i];
    float bv = bias[c];
    float acc[16];
#pragma unroll
    for (int i = 0; i < 16; i++) acc[i] = bv;
    int h0 = ty * 16;
#pragma unroll
    for (int rr = 0; rr < 22; rr++) {
        float v[7];
#pragma unroll
        for (int kw = 0; kw < 7; kw++) v[kw] = img[(h0 + rr) * 72 + tx + kw];
#pragma unroll
        for (int kh = 0; kh < 7; kh++) {
            int o = rr - kh;
            if (o >= 0 && o <= 15) {
                float dot = v[0] * wt[kh * 7];
#pragma unroll
                for (int kw = 1; kw < 7; kw++) dot += v[kw] * wt[kh * 7 + kw];
                acc[o] += dot;
            }
        }
    }
    unsigned short* dst = out + (size_t)bc * 4096;
#pragma unroll
    for (int i = 0; i < 16; i++)
        dst[(h0 + i) * 64 + tx] = f2b(acc[i]);
}

// ---------------- final: out = x(f32) + attn(bf16) + y2^T(bf16) -> f32; 4 tiles/block ---------
__global__ __launch_bounds__(256) void final_add(const float* __restrict__ x,
                                                 const unsigned short* __restrict__ attn,
                                                 const unsigned short* __restrict__ y2,
                                                 float* __restrict__ out) {
    __shared__ unsigned short tile[32][36];
    int b = blockIdx.z;
    int c0 = blockIdx.x * 32;
    int n0b = blockIdx.y * 128;
    int t = threadIdx.x;
#pragma unroll
    for (int nt = 0; nt < 4; ++nt) {
        int n0 = n0b + nt * 32;
        __syncthreads();
        {
            int c = t >> 3, n4 = (t & 7) * 4;
            ushort4 v = *(const ushort4*)&y2[((size_t)(b * 512 + c0 + c)) * 4096 + n0 + n4];
            tile[c][n4] = v.x; tile[c][n4 + 1] = v.y; tile[c][n4 + 2] = v.z; tile[c][n4 + 3] = v.w;
        }
        __syncthreads();
        int nl = t >> 3, cl = (t & 7) * 4;
        size_t idx = ((size_t)(b * 4096 + n0 + nl)) * 512 + c0 + cl;
        float4 xv = *(const float4*)&x[idx];
        ushort4 av = *(const ushort4*)&attn[idx];
        float4 o;
        o.x = xv.x + b2f(av.x) + b2f(tile[cl][nl]);
        o.y = xv.y + b2f(av.y) + b2f(tile[cl + 1][nl]);
        o.z = xv.z + b2f(av.z) + b2f(tile[cl + 2][nl]);
        o.w = xv.w + b2f(av.w) + b2f(tile[cl + 3][nl]);
        *(float4*)&out[idx] = o;
    }
}

// ------------------------------------------------------------------------------------------------
extern "C" void kernel_launch(void* const* d_in, const int* in_sizes, int n_in,
                              void* d_out, int out_size, void* d_ws, size_t ws_size,
                              hipStream_t stream) {
    const float* x     = (const float*)d_in[0];
    const float* qkv_w = (const float*)d_in[1];
    const float* qkv_b = (const float*)d_in[2];
    const float* out_w = (const float*)d_in[3];
    const float* out_b = (const float*)d_in[4];
    const float* pre_g = (const float*)d_in[5];
    const float* pre_b = (const float*)d_in[6];
    const float* lcm_g = (const float*)d_in[7];
    const float* lcm_b = (const float*)d_in[8];
    const float* ci_w  = (const float*)d_in[9];
    const float* ci_b  = (const float*)d_in[10];
    const float* bn_g  = (const float*)d_in[11];
    const float* bn_b  = (const float*)d_in[12];
    const float* co_w  = (const float*)d_in[13];
    const float* co_b  = (const float*)d_in[14];

    char* ws = (char*)d_ws;
    const size_t SLOT = 33554432;  // 32768*512*2 bytes (bf16)
    unsigned short* S0 = (unsigned short*)(ws);               // q -> attn -> xi -> y2
    unsigned short* S1 = (unsigned short*)(ws + SLOT);        // kT -> attn_out(bf16)
    unsigned short* S2 = (unsigned short*)(ws + 2 * SLOT);    // vT -> y
    const size_t MISC = 3 * SLOT;                             // 96MB
    unsigned short* wT1 = (unsigned short*)(ws + MISC);                 // 1.5MB bf16
    unsigned short* wT2 = (unsigned short*)(ws + MISC + 1572864);       // 0.5MB bf16
    float* bn_sum       = (float*)(ws + MISC + 2097152);                // 2KB
    float* bn_sumsq     = (float*)(ws + MISC + 2097152 + 2048);         // 2KB
    float2* bnab        = (float2*)(ws + MISC + 2097152 + 4096);        // 4KB
    float* ksp          = (float*)(ws + MISC + 2105344);                // 128KB
    float* outp         = (float*)d_out;

    // d_out doubles as scratch before final_add fully overwrites it:
    unsigned short* normed = (unsigned short*)d_out;                    // 32MB bf16
    float* kvp             = (float*)((char*)d_out + SLOT);             // 8MB fp32 partials
    unsigned short* kvhT   = (unsigned short*)((char*)d_out + SLOT + 8388608);   // 512KB
    unsigned short* kvlT   = kvhT + 262144;                             // 512KB
    unsigned short* nrmp   = kvlT + 262144;                             // 16KB

    dim3 tb(32, 8);
    transpose_f2b<<<dim3(48, 16), tb, 0, stream>>>(qkv_w, wT1, 512, 1536);
    transpose_f2b<<<dim3(16, 16), tb, 0, stream>>>(out_w, wT2, 512, 512);
    zero_fill<<<4, 256, 0, stream>>>(bn_sum, 1024);  // bn_sum + bn_sumsq
    ln_apply<<<8192, 256, 0, stream>>>(x, pre_g, pre_b, normed);
    // M=32768/256=128, N=1536/128=12 -> 1536 blocks (%8==0); writes q + kT + vT
    gemm256<12, true><<<1536, 512, 0, stream>>>(normed, wT1, qkv_b, S0, S1, S2);
    kv_part<<<dim3(64, 8), 256, 0, stream>>>(S1, S2, kvp, ksp);
    kv_reduce<<<1024, 256, 0, stream>>>(kvp, ksp, kvhT, kvlT, nrmp);
    attn_mfma<<<dim3(16, 64), 256, 0, stream>>>(S0, kvhT, kvlT, nrmp);
    // M=128, N=512/128=4 -> 512 blocks (%8==0)
    gemm256<4, false><<<512, 512, 0, stream>>>(S0, wT2, out_b, S1, S1, S1);
    // fused LN2 + transpose: S1 [B,N,C] -> S0 [B,C,N]
    ln2_transpose<<<512, 256, 0, stream>>>(S1, lcm_g, lcm_b, S0);
    dwconv7_gelu<<<4096, 256, 0, stream>>>(S0, ci_w, ci_b, S2, bn_sum, bn_sumsq);
    bn_finalize<<<2, 256, 0, stream>>>(bn_sum, bn_sumsq, bn_g, bn_b, bnab);
    dwconv7_bn<<<4096, 256, 0, stream>>>(S2, bnab, co_w, co_b, S0);
    final_add<<<dim3(16, 32, 8), 256, 0, stream>>>(x, S1, S0, outp);
}